// Round 4
// baseline (558.933 us; speedup 1.0000x reference)
//
#include <hip/hip_runtime.h>

// NodeModel GNN: edge MLP (96->128->128->64 + LN) -> scatter_mean -> node MLP
// (128->128->128->64 + LN).  bf16 MFMA (16x16x32), fp32 accumulate.
//
// R4 (bisect of R3 failure): separate atile/hid LDS buffers restored (the
// R2-exercised hazard pattern). KEPT from R3: fragment-ordered weight image
// read directly from global (L2-resident), biases from global, dest ids via
// __shfl, non-persistent grids. LDS 61.4KB (edge) / 69.6KB (node) => 2
// blocks/CU (vs R2's 1).
//
// MFMA layouts (verified):
//   A-frag:  A[m = lane&15][k = (lane>>4)*8 + j]
//   B-frag:  B[k = (lane>>4)*8 + j][n = lane&15]
//   C/D:     col n = lane&15, row m = (lane>>4)*4 + reg

#define NNODES 50000
#define NEDGES 800000

typedef __bf16 bf16;
typedef __bf16 __attribute__((ext_vector_type(4))) bf16x4;
typedef __bf16 __attribute__((ext_vector_type(8))) bf16x8;
typedef float __attribute__((ext_vector_type(4))) f32x4;

__device__ __forceinline__ f32x4 mfma_bf16(bf16x8 a, bf16x8 b, f32x4 c) {
    return __builtin_amdgcn_mfma_f32_16x16x32_bf16(a, b, c, 0, 0, 0);
}

// ---- fragment-ordered weight image ----
// per layer: block (ks*NT + nt) holds 64 lanes x 8 bf16 (1KB), lane-ordered.
// value at (layer, ks, nt, lane, j) = W[k][n], k = ks*32+(lane>>4)*8+j,
// n = nt*16+(lane&15), W row-major [K][N].
// e0: m1w0 K=96  N=128 KS=3 @ 0      (12288 elems)
// e1: m1w1 K=128 N=128 KS=4 @ 12288  (16384)
// e2: m1w2 K=128 N=64  KS=4 @ 28672  ( 8192)
// n0: m2w0 K=128 N=128 KS=4 @ 36864  (16384)
// n1: m2w1 K=128 N=128 KS=4 @ 53248  (16384)
// n2: m2w2 K=128 N=64  KS=4 @ 69632  ( 8192)  -> total 77824 elems
__global__ void prep_weights(const float* __restrict__ w10, const float* __restrict__ w11,
                             const float* __restrict__ w12, const float* __restrict__ w20,
                             const float* __restrict__ w21, const float* __restrict__ w22,
                             bf16* __restrict__ img) {
    int idx = blockIdx.x * 256 + threadIdx.x;
    if (idx >= 77824) return;
    const float* w; int N; int t;
    if (idx < 12288)      { w = w10; N = 128; t = idx; }
    else if (idx < 28672) { w = w11; N = 128; t = idx - 12288; }
    else if (idx < 36864) { w = w12; N = 64;  t = idx - 28672; }
    else if (idx < 53248) { w = w20; N = 128; t = idx - 36864; }
    else if (idx < 69632) { w = w21; N = 128; t = idx - 53248; }
    else                  { w = w22; N = 64;  t = idx - 69632; }
    int j = t & 7, lane = (t >> 3) & 63, blk = t >> 9;
    int NT = N >> 4;
    int nt = blk % NT, ks = blk / NT;
    int k = ks * 32 + ((lane >> 4) << 3) + j;
    int n = nt * 16 + (lane & 15);
    img[idx] = (bf16)w[k * N + n];
}

// ---- counting sort of edges by destination ----
__global__ void hist_kernel(const int* __restrict__ col, int* __restrict__ hist) {
    int i = blockIdx.x * 512 + threadIdx.x;
    if (i < NEDGES) atomicAdd(hist + col[i], 1);
}

__global__ void scanA(const int* __restrict__ hist, int* __restrict__ off,
                      int* __restrict__ csum) {
    __shared__ int sd[512];
    int t = threadIdx.x, i = blockIdx.x * 512 + t;
    int v = (i < NNODES) ? hist[i] : 0;
    sd[t] = v;
    __syncthreads();
    for (int o2 = 1; o2 < 512; o2 <<= 1) {
        int x = (t >= o2) ? sd[t - o2] : 0;
        __syncthreads();
        sd[t] += x;
        __syncthreads();
    }
    if (i < NNODES) off[i] = sd[t] - v;  // exclusive
    if (t == 511) csum[blockIdx.x] = sd[511];
}

__global__ void scanB(int* __restrict__ csum) {  // 1 block, 98 live
    __shared__ int sd[128];
    int t = threadIdx.x;
    int v = (t < 98) ? csum[t] : 0;
    sd[t] = v;
    __syncthreads();
    for (int o2 = 1; o2 < 128; o2 <<= 1) {
        int x = (t >= o2) ? sd[t - o2] : 0;
        __syncthreads();
        sd[t] += x;
        __syncthreads();
    }
    if (t < 98) csum[t] = sd[t] - v;  // exclusive chunk offsets
}

__global__ void scanC(int* __restrict__ off, const int* __restrict__ csum) {
    int i = blockIdx.x * 512 + threadIdx.x;
    if (i < NNODES) off[i] += csum[blockIdx.x];
}

// prd[pos] = {edge id, row | dest<<16}, pos dest-sorted
__global__ void scatter_kernel(const int* __restrict__ eidx, int* __restrict__ off,
                               int2* __restrict__ prd) {
    int i = blockIdx.x * 512 + threadIdx.x;
    if (i < NEDGES) {
        int r = eidx[i], d = eidx[NEDGES + i];
        int pos = atomicAdd(off + d, 1);
        prd[pos] = make_int2(i, r | (d << 16));
    }
}

__global__ __launch_bounds__(256, 2) void edge_mlp(
    const float* __restrict__ x, const int2* __restrict__ prd,
    const float* __restrict__ eattr, const bf16* __restrict__ wimg,
    const float* __restrict__ b0g, const float* __restrict__ b1g,
    const float* __restrict__ b2g, const float* __restrict__ lng,
    const float* __restrict__ lnb, float* __restrict__ agg) {
    __shared__ __align__(16) bf16 atile[128 * 104];
    __shared__ __align__(16) bf16 hid[128 * 136];

    const int tid = threadIdx.x;
    const int lane = tid & 63;
    const int wv = tid >> 6;
    const int col16 = lane & 15;
    const int quad = lane >> 4;

    float b0r[8], b1r[8], b2r[4], gr[4], br[4];
#pragma unroll
    for (int i = 0; i < 8; i++) { b0r[i] = b0g[i * 16 + col16]; b1r[i] = b1g[i * 16 + col16]; }
#pragma unroll
    for (int i = 0; i < 4; i++) {
        b2r[i] = b2g[i * 16 + col16];
        gr[i] = lng[i * 16 + col16];
        br[i] = lnb[i * 16 + col16];
    }

    const bf16* wl = wimg + (size_t)lane * 8;  // lane base; frag blocks stride 512 elems
    const f32x4 vzero = {0.0f, 0.0f, 0.0f, 0.0f};
    const int r0 = wv * 32 + col16;     // A-frag row (mt=0)
    const int rw = wv * 32 + quad * 4;  // C/D row base (+ mt*16 + reg)
    const int sbase = blockIdx.x * 128;

    // ---- stage A tile: concat(x[row], eattr) for sorted slot s ----
    int vreg;  // row | dest<<16 of the row this thread staged (wave-local row = lane>>1)
    {
        const int el = tid >> 1, half = tid & 1;
        int2 v = prd[sbase + el];
        vreg = v.y;
        const int r = v.y & 0xFFFF;
        const float4* xs = (const float4*)(x + (size_t)r * 64);
        bf16* arow = atile + el * 104;
#pragma unroll
        for (int j = 0; j < 8; j++) {
            float4 vv = xs[half * 8 + j];
            bf16x4 u = {(bf16)vv.x, (bf16)vv.y, (bf16)vv.z, (bf16)vv.w};
            *(bf16x4*)(arow + half * 32 + j * 4) = u;
        }
        const float4* es = (const float4*)(eattr + (size_t)v.x * 32);
#pragma unroll
        for (int j = 0; j < 4; j++) {
            float4 vv = es[half * 4 + j];
            bf16x4 u = {(bf16)vv.x, (bf16)vv.y, (bf16)vv.z, (bf16)vv.w};
            *(bf16x4*)(arow + 64 + half * 16 + j * 4) = u;
        }
    }
    // wave staged exactly its own 32 rows -> no barrier needed anywhere

    // ---- layer 1: [32x96] @ [96x128], atile -> hid ----
    f32x4 acc1[2][8];
#pragma unroll
    for (int mt = 0; mt < 2; mt++)
#pragma unroll
        for (int nt = 0; nt < 8; nt++) acc1[mt][nt] = vzero;
#pragma unroll
    for (int ks = 0; ks < 3; ks++) {
        bf16x8 a0 = *(const bf16x8*)(atile + r0 * 104 + ks * 32 + quad * 8);
        bf16x8 a1 = *(const bf16x8*)(atile + (r0 + 16) * 104 + ks * 32 + quad * 8);
#pragma unroll
        for (int nt = 0; nt < 8; nt++) {
            bf16x8 b = *(const bf16x8*)(wl + (ks * 8 + nt) * 512);
            acc1[0][nt] = mfma_bf16(a0, b, acc1[0][nt]);
            acc1[1][nt] = mfma_bf16(a1, b, acc1[1][nt]);
        }
    }
#pragma unroll
    for (int mt = 0; mt < 2; mt++)
#pragma unroll
        for (int nt = 0; nt < 8; nt++)
#pragma unroll
            for (int rg = 0; rg < 4; rg++) {
                float v = acc1[mt][nt][rg] + b0r[nt];
                v = (v > 0.0f) ? v : 0.01f * v;
                hid[(rw + mt * 16 + rg) * 136 + nt * 16 + col16] = (bf16)v;
            }

    // ---- layer 2: [32x128] @ [128x128], hid -> hid ----
    bf16x8 a2[2][4];
#pragma unroll
    for (int mt = 0; mt < 2; mt++)
#pragma unroll
        for (int ks = 0; ks < 4; ks++)
            a2[mt][ks] = *(const bf16x8*)(hid + (r0 + mt * 16) * 136 + ks * 32 + quad * 8);
    f32x4 acc2[2][8];
#pragma unroll
    for (int mt = 0; mt < 2; mt++)
#pragma unroll
        for (int nt = 0; nt < 8; nt++) acc2[mt][nt] = vzero;
#pragma unroll
    for (int ks = 0; ks < 4; ks++) {
#pragma unroll
        for (int nt = 0; nt < 8; nt++) {
            bf16x8 b = *(const bf16x8*)(wl + 12288 + (ks * 8 + nt) * 512);
            acc2[0][nt] = mfma_bf16(a2[0][ks], b, acc2[0][nt]);
            acc2[1][nt] = mfma_bf16(a2[1][ks], b, acc2[1][nt]);
        }
    }
#pragma unroll
    for (int mt = 0; mt < 2; mt++)
#pragma unroll
        for (int nt = 0; nt < 8; nt++)
#pragma unroll
            for (int rg = 0; rg < 4; rg++) {
                float v = acc2[mt][nt][rg] + b1r[nt];
                v = (v > 0.0f) ? v : 0.01f * v;
                hid[(rw + mt * 16 + rg) * 136 + nt * 16 + col16] = (bf16)v;
            }

    // ---- layer 3: [32x128] @ [128x64] ----
    bf16x8 a3[2][4];
#pragma unroll
    for (int mt = 0; mt < 2; mt++)
#pragma unroll
        for (int ks = 0; ks < 4; ks++)
            a3[mt][ks] = *(const bf16x8*)(hid + (r0 + mt * 16) * 136 + ks * 32 + quad * 8);
    f32x4 acc3[2][4];
#pragma unroll
    for (int mt = 0; mt < 2; mt++)
#pragma unroll
        for (int nt = 0; nt < 4; nt++) acc3[mt][nt] = vzero;
#pragma unroll
    for (int ks = 0; ks < 4; ks++) {
#pragma unroll
        for (int nt = 0; nt < 4; nt++) {
            bf16x8 b = *(const bf16x8*)(wl + 28672 + (ks * 4 + nt) * 512);
            acc3[0][nt] = mfma_bf16(a3[0][ks], b, acc3[0][nt]);
            acc3[1][nt] = mfma_bf16(a3[1][ks], b, acc3[1][nt]);
        }
    }

    // ---- epilogue: bias + lrelu + LN(64) + run-merged atomic scatter ----
#pragma unroll
    for (int mt = 0; mt < 2; mt++) {
        float vals[4][4];  // [nt][rg]
        float s1[4] = {0.f, 0.f, 0.f, 0.f}, s2[4] = {0.f, 0.f, 0.f, 0.f};
#pragma unroll
        for (int nt = 0; nt < 4; nt++)
#pragma unroll
            for (int rg = 0; rg < 4; rg++) {
                float v = acc3[mt][nt][rg] + b2r[nt];
                v = (v > 0.0f) ? v : 0.01f * v;
                vals[nt][rg] = v;
                s1[rg] += v;
                s2[rg] += v * v;
            }
#pragma unroll
        for (int off2 = 1; off2 < 16; off2 <<= 1) {
#pragma unroll
            for (int rg = 0; rg < 4; rg++) {
                s1[rg] += __shfl_xor(s1[rg], off2);
                s2[rg] += __shfl_xor(s2[rg], off2);
            }
        }
        float o[4][4];
        int dr[4];
#pragma unroll
        for (int rg = 0; rg < 4; rg++) {
            float mu = s1[rg] * 0.015625f;
            float var = s2[rg] * 0.015625f - mu * mu;
            float rstd = rsqrtf(var + 1e-5f);
            // dest of wave-local row (mt*16+quad*4+rg), staged by lane 2*row
            dr[rg] = ((unsigned)__shfl(vreg, (mt * 16 + quad * 4 + rg) << 1)) >> 16;
#pragma unroll
            for (int nt = 0; nt < 4; nt++)
                o[nt][rg] = (vals[nt][rg] - mu) * rstd * gr[nt] + br[nt];
        }
        // run-merge consecutive equal destinations (edges dest-sorted)
        float run0 = o[0][0], run1 = o[1][0], run2 = o[2][0], run3 = o[3][0];
        int cur = dr[0];
#pragma unroll
        for (int rg = 1; rg < 4; rg++) {
            if (dr[rg] != cur) {
                float* dst = agg + (size_t)cur * 64 + col16;
                atomicAdd(dst, run0); atomicAdd(dst + 16, run1);
                atomicAdd(dst + 32, run2); atomicAdd(dst + 48, run3);
                run0 = o[0][rg]; run1 = o[1][rg]; run2 = o[2][rg]; run3 = o[3][rg];
                cur = dr[rg];
            } else {
                run0 += o[0][rg]; run1 += o[1][rg]; run2 += o[2][rg]; run3 += o[3][rg];
            }
        }
        float* dst = agg + (size_t)cur * 64 + col16;
        atomicAdd(dst, run0); atomicAdd(dst + 16, run1);
        atomicAdd(dst + 32, run2); atomicAdd(dst + 48, run3);
    }
}

__global__ __launch_bounds__(256, 2) void node_mlp(
    const float* __restrict__ x, const float* __restrict__ agg,
    const int* __restrict__ hist, const bf16* __restrict__ wimg,
    const float* __restrict__ b0g, const float* __restrict__ b1g,
    const float* __restrict__ b2g, const float* __restrict__ lng,
    const float* __restrict__ lnb, float* __restrict__ out) {
    __shared__ __align__(16) bf16 atile[128 * 136];
    __shared__ __align__(16) bf16 hid[128 * 136];

    const int tid = threadIdx.x;
    const int lane = tid & 63;
    const int wv = tid >> 6;
    const int col16 = lane & 15;
    const int quad = lane >> 4;

    float b0r[8], b1r[8], b2r[4], gr[4], br[4];
#pragma unroll
    for (int i = 0; i < 8; i++) { b0r[i] = b0g[i * 16 + col16]; b1r[i] = b1g[i * 16 + col16]; }
#pragma unroll
    for (int i = 0; i < 4; i++) {
        b2r[i] = b2g[i * 16 + col16];
        gr[i] = lng[i * 16 + col16];
        br[i] = lnb[i * 16 + col16];
    }

    const bf16* wl = wimg + 36864 + (size_t)lane * 8;
    const f32x4 vzero = {0.0f, 0.0f, 0.0f, 0.0f};
    const int r0 = wv * 32 + col16;
    const int rw = wv * 32 + quad * 4;
    const int nbase = blockIdx.x * 128;

    // ---- stage A: concat(x[i], agg[i]/max(cnt,1)) -> [128 x 136] ----
    {
        const int el = tid >> 1, half = tid & 1;
        int i = nbase + el;
        if (i >= NNODES) i = NNODES - 1;  // clamp; tail rows never stored
        const float4* xs = (const float4*)(x + (size_t)i * 64);
        bf16* arow = atile + el * 136;
#pragma unroll
        for (int j = 0; j < 8; j++) {
            float4 v = xs[half * 8 + j];
            bf16x4 u = {(bf16)v.x, (bf16)v.y, (bf16)v.z, (bf16)v.w};
            *(bf16x4*)(arow + half * 32 + j * 4) = u;
        }
        int c = hist[i];
        float inv = 1.0f / (float)(c > 1 ? c : 1);
        const float4* as = (const float4*)(agg + (size_t)i * 64);
#pragma unroll
        for (int j = 0; j < 8; j++) {
            float4 v = as[half * 8 + j];
            bf16x4 u = {(bf16)(v.x * inv), (bf16)(v.y * inv), (bf16)(v.z * inv), (bf16)(v.w * inv)};
            *(bf16x4*)(arow + 64 + half * 32 + j * 4) = u;
        }
    }

    // ---- layer 1: [32x128] @ [128x128], atile -> hid ----
    f32x4 acc1[2][8];
#pragma unroll
    for (int mt = 0; mt < 2; mt++)
#pragma unroll
        for (int nt = 0; nt < 8; nt++) acc1[mt][nt] = vzero;
#pragma unroll
    for (int ks = 0; ks < 4; ks++) {
        bf16x8 a0 = *(const bf16x8*)(atile + r0 * 136 + ks * 32 + quad * 8);
        bf16x8 a1 = *(const bf16x8*)(atile + (r0 + 16) * 136 + ks * 32 + quad * 8);
#pragma unroll
        for (int nt = 0; nt < 8; nt++) {
            bf16x8 b = *(const bf16x8*)(wl + (ks * 8 + nt) * 512);
            acc1[0][nt] = mfma_bf16(a0, b, acc1[0][nt]);
            acc1[1][nt] = mfma_bf16(a1, b, acc1[1][nt]);
        }
    }
#pragma unroll
    for (int mt = 0; mt < 2; mt++)
#pragma unroll
        for (int nt = 0; nt < 8; nt++)
#pragma unroll
            for (int rg = 0; rg < 4; rg++) {
                float v = acc1[mt][nt][rg] + b0r[nt];
                v = (v > 0.0f) ? v : 0.01f * v;
                hid[(rw + mt * 16 + rg) * 136 + nt * 16 + col16] = (bf16)v;
            }

    // ---- layer 2: hid -> hid ----
    bf16x8 a2[2][4];
#pragma unroll
    for (int mt = 0; mt < 2; mt++)
#pragma unroll
        for (int ks = 0; ks < 4; ks++)
            a2[mt][ks] = *(const bf16x8*)(hid + (r0 + mt * 16) * 136 + ks * 32 + quad * 8);
    f32x4 acc2[2][8];
#pragma unroll
    for (int mt = 0; mt < 2; mt++)
#pragma unroll
        for (int nt = 0; nt < 8; nt++) acc2[mt][nt] = vzero;
#pragma unroll
    for (int ks = 0; ks < 4; ks++) {
#pragma unroll
        for (int nt = 0; nt < 8; nt++) {
            bf16x8 b = *(const bf16x8*)(wl + 16384 + (ks * 8 + nt) * 512);
            acc2[0][nt] = mfma_bf16(a2[0][ks], b, acc2[0][nt]);
            acc2[1][nt] = mfma_bf16(a2[1][ks], b, acc2[1][nt]);
        }
    }
#pragma unroll
    for (int mt = 0; mt < 2; mt++)
#pragma unroll
        for (int nt = 0; nt < 8; nt++)
#pragma unroll
            for (int rg = 0; rg < 4; rg++) {
                float v = acc2[mt][nt][rg] + b1r[nt];
                v = (v > 0.0f) ? v : 0.01f * v;
                hid[(rw + mt * 16 + rg) * 136 + nt * 16 + col16] = (bf16)v;
            }

    // ---- layer 3 ----
    bf16x8 a3[2][4];
#pragma unroll
    for (int mt = 0; mt < 2; mt++)
#pragma unroll
        for (int ks = 0; ks < 4; ks++)
            a3[mt][ks] = *(const bf16x8*)(hid + (r0 + mt * 16) * 136 + ks * 32 + quad * 8);
    f32x4 acc3[2][4];
#pragma unroll
    for (int mt = 0; mt < 2; mt++)
#pragma unroll
        for (int nt = 0; nt < 4; nt++) acc3[mt][nt] = vzero;
#pragma unroll
    for (int ks = 0; ks < 4; ks++) {
#pragma unroll
        for (int nt = 0; nt < 4; nt++) {
            bf16x8 b = *(const bf16x8*)(wl + 32768 + (ks * 4 + nt) * 512);
            acc3[0][nt] = mfma_bf16(a3[0][ks], b, acc3[0][nt]);
            acc3[1][nt] = mfma_bf16(a3[1][ks], b, acc3[1][nt]);
        }
    }

    // ---- epilogue: bias + lrelu + LN + store ----
#pragma unroll
    for (int mt = 0; mt < 2; mt++) {
        float vals[4][4];
        float s1[4] = {0.f, 0.f, 0.f, 0.f}, s2[4] = {0.f, 0.f, 0.f, 0.f};
#pragma unroll
        for (int nt = 0; nt < 4; nt++)
#pragma unroll
            for (int rg = 0; rg < 4; rg++) {
                float v = acc3[mt][nt][rg] + b2r[nt];
                v = (v > 0.0f) ? v : 0.01f * v;
                vals[nt][rg] = v;
                s1[rg] += v;
                s2[rg] += v * v;
            }
#pragma unroll
        for (int off2 = 1; off2 < 16; off2 <<= 1) {
#pragma unroll
            for (int rg = 0; rg < 4; rg++) {
                s1[rg] += __shfl_xor(s1[rg], off2);
                s2[rg] += __shfl_xor(s2[rg], off2);
            }
        }
#pragma unroll
        for (int rg = 0; rg < 4; rg++) {
            float mu = s1[rg] * 0.015625f;
            float var = s2[rg] * 0.015625f - mu * mu;
            float rstd = rsqrtf(var + 1e-5f);
            int i = nbase + rw + mt * 16 + rg;
            if (i < NNODES) {
#pragma unroll
                for (int nt = 0; nt < 4; nt++) {
                    float o = (vals[nt][rg] - mu) * rstd * gr[nt] + br[nt];
                    out[(size_t)i * 64 + nt * 16 + col16] = o;
                }
            }
        }
    }
}

extern "C" void kernel_launch(void* const* d_in, const int* in_sizes, int n_in,
                              void* d_out, int out_size, void* d_ws, size_t ws_size,
                              hipStream_t stream) {
    (void)in_sizes; (void)n_in; (void)out_size; (void)ws_size;
    const float* x     = (const float*)d_in[0];
    const int*   eidx  = (const int*)d_in[1];
    const float* eattr = (const float*)d_in[2];
    const float* m1w0 = (const float*)d_in[5];
    const float* m1b0 = (const float*)d_in[6];
    const float* m1w1 = (const float*)d_in[7];
    const float* m1b1 = (const float*)d_in[8];
    const float* m1w2 = (const float*)d_in[9];
    const float* m1b2 = (const float*)d_in[10];
    const float* ln1g = (const float*)d_in[11];
    const float* ln1b = (const float*)d_in[12];
    const float* m2w0 = (const float*)d_in[13];
    const float* m2b0 = (const float*)d_in[14];
    const float* m2w1 = (const float*)d_in[15];
    const float* m2b1 = (const float*)d_in[16];
    const float* m2w2 = (const float*)d_in[17];
    const float* m2b2 = (const float*)d_in[18];
    const float* ln2g = (const float*)d_in[19];
    const float* ln2b = (const float*)d_in[20];

    // ---- workspace layout ----
    char* ws = (char*)d_ws;
    float* agg  = (float*)ws;                          // 12,800,000 B
    int*   hist = (int*)(ws + 12800000);               //    200,000 B
    int*   off  = (int*)(ws + 13000000);               //    200,000 B
    int*   csum = (int*)(ws + 13200000);               //        512 B
    int2*  prd  = (int2*)(ws + 13200512);              //  6,400,000 B
    bf16*  wimg = (bf16*)(ws + 19600512);              //    155,648 B

    hipMemsetAsync(d_ws, 0, 13000000, stream);  // agg + hist
    prep_weights<<<304, 256, 0, stream>>>(m1w0, m1w1, m1w2, m2w0, m2w1, m2w2, wimg);
    hist_kernel<<<1563, 512, 0, stream>>>(eidx + NEDGES, hist);
    scanA<<<98, 512, 0, stream>>>(hist, off, csum);
    scanB<<<1, 128, 0, stream>>>(csum);
    scanC<<<98, 512, 0, stream>>>(off, csum);
    scatter_kernel<<<1563, 512, 0, stream>>>(eidx, off, prd);
    edge_mlp<<<6250, 256, 0, stream>>>(x, prd, eattr, wimg, m1b0, m1b1, m1b2,
                                       ln1g, ln1b, agg);
    node_mlp<<<391, 256, 0, stream>>>(x, agg, hist, wimg,
                                      m2b0, m2b1, m2b2, ln2g, ln2b, (float*)d_out);
}

// Round 6
// 552.083 us; speedup vs baseline: 1.0124x; 1.0124x over previous
//
#include <hip/hip_runtime.h>

// NodeModel GNN: edge MLP (96->128->128->64 + LN) -> scatter_mean -> node MLP
// (128->128->128->64 + LN).  bf16 MFMA (16x16x32), fp32 accumulate.
//
// R6 BISECT: edge_mlp is R4's exact proven kernel (LDS staging, 256 thr).
// node_mlp is R5's register-gather 64-thread version. scanC stays folded into
// scatter (analytically safe: dest travels with the edge in prd; cnt comes
// from the histogram -- sort order cannot affect correctness).
//
// MFMA layouts (verified):
//   A-frag:  A[m = lane&15][k = (lane>>4)*8 + j]
//   B-frag:  B[k = (lane>>4)*8 + j][n = lane&15]
//   C/D:     col n = lane&15, row m = (lane>>4)*4 + reg

#define NNODES 50000
#define NEDGES 800000

typedef __bf16 bf16;
typedef __bf16 __attribute__((ext_vector_type(4))) bf16x4;
typedef __bf16 __attribute__((ext_vector_type(8))) bf16x8;
typedef float __attribute__((ext_vector_type(4))) f32x4;

__device__ __forceinline__ f32x4 mfma_bf16(bf16x8 a, bf16x8 b, f32x4 c) {
    return __builtin_amdgcn_mfma_f32_16x16x32_bf16(a, b, c, 0, 0, 0);
}

__device__ __forceinline__ bf16x8 pack8(float4 a, float4 b) {
    bf16x8 r;
    r[0] = (bf16)a.x; r[1] = (bf16)a.y; r[2] = (bf16)a.z; r[3] = (bf16)a.w;
    r[4] = (bf16)b.x; r[5] = (bf16)b.y; r[6] = (bf16)b.z; r[7] = (bf16)b.w;
    return r;
}

// ---- fragment-ordered weight image ----
// per layer: block (ks*NT + nt) holds 64 lanes x 8 bf16 (1KB), lane-ordered.
// value at (layer, ks, nt, lane, j) = W[k][n], k = ks*32+(lane>>4)*8+j,
// n = nt*16+(lane&15), W row-major [K][N].
// e0 @0 (12288) | e1 @12288 (16384) | e2 @28672 (8192)
// n0 @36864     | n1 @53248        | n2 @69632 -> total 77824 elems
__global__ void prep_weights(const float* __restrict__ w10, const float* __restrict__ w11,
                             const float* __restrict__ w12, const float* __restrict__ w20,
                             const float* __restrict__ w21, const float* __restrict__ w22,
                             bf16* __restrict__ img) {
    int idx = blockIdx.x * 256 + threadIdx.x;
    if (idx >= 77824) return;
    const float* w; int N; int t;
    if (idx < 12288)      { w = w10; N = 128; t = idx; }
    else if (idx < 28672) { w = w11; N = 128; t = idx - 12288; }
    else if (idx < 36864) { w = w12; N = 64;  t = idx - 28672; }
    else if (idx < 53248) { w = w20; N = 128; t = idx - 36864; }
    else if (idx < 69632) { w = w21; N = 128; t = idx - 53248; }
    else                  { w = w22; N = 64;  t = idx - 69632; }
    int j = t & 7, lane = (t >> 3) & 63, blk = t >> 9;
    int NT = N >> 4;
    int nt = blk % NT, ks = blk / NT;
    int k = ks * 32 + ((lane >> 4) << 3) + j;
    int n = nt * 16 + (lane & 15);
    img[idx] = (bf16)w[k * N + n];
}

// ---- counting sort of edges by destination ----
__global__ void hist_kernel(const int* __restrict__ col, int* __restrict__ hist) {
    int i = blockIdx.x * 512 + threadIdx.x;
    if (i < NEDGES) atomicAdd(hist + col[i], 1);
}

__global__ void scanA(const int* __restrict__ hist, int* __restrict__ off,
                      int* __restrict__ csum) {
    __shared__ int sd[512];
    int t = threadIdx.x, i = blockIdx.x * 512 + t;
    int v = (i < NNODES) ? hist[i] : 0;
    sd[t] = v;
    __syncthreads();
    for (int o2 = 1; o2 < 512; o2 <<= 1) {
        int x = (t >= o2) ? sd[t - o2] : 0;
        __syncthreads();
        sd[t] += x;
        __syncthreads();
    }
    if (i < NNODES) off[i] = sd[t] - v;  // chunk-local exclusive
    if (t == 511) csum[blockIdx.x] = sd[511];
}

__global__ void scanB(int* __restrict__ csum) {  // 1 block, 98 live
    __shared__ int sd[128];
    int t = threadIdx.x;
    int v = (t < 98) ? csum[t] : 0;
    sd[t] = v;
    __syncthreads();
    for (int o2 = 1; o2 < 128; o2 <<= 1) {
        int x = (t >= o2) ? sd[t - o2] : 0;
        __syncthreads();
        sd[t] += x;
        __syncthreads();
    }
    if (t < 98) csum[t] = sd[t] - v;  // exclusive chunk offsets
}

// prd[pos] = {edge id, row | dest<<16}, pos dest-sorted.
// pos = chunk-local rank (atomic on off) + chunk base (csum).
__global__ void scatter_kernel(const int* __restrict__ eidx, int* __restrict__ off,
                               const int* __restrict__ csum, int2* __restrict__ prd) {
    int i = blockIdx.x * 512 + threadIdx.x;
    if (i < NEDGES) {
        int r = eidx[i], d = eidx[NEDGES + i];
        int pos = atomicAdd(off + d, 1) + csum[d >> 9];
        prd[pos] = make_int2(i, r | (d << 16));
    }
}

// ================= edge_mlp: EXACT R4 proven kernel =================
__global__ __launch_bounds__(256, 2) void edge_mlp(
    const float* __restrict__ x, const int2* __restrict__ prd,
    const float* __restrict__ eattr, const bf16* __restrict__ wimg,
    const float* __restrict__ b0g, const float* __restrict__ b1g,
    const float* __restrict__ b2g, const float* __restrict__ lng,
    const float* __restrict__ lnb, float* __restrict__ agg) {
    __shared__ __align__(16) bf16 atile[128 * 104];
    __shared__ __align__(16) bf16 hid[128 * 136];

    const int tid = threadIdx.x;
    const int lane = tid & 63;
    const int wv = tid >> 6;
    const int col16 = lane & 15;
    const int quad = lane >> 4;

    float b0r[8], b1r[8], b2r[4], gr[4], br[4];
#pragma unroll
    for (int i = 0; i < 8; i++) { b0r[i] = b0g[i * 16 + col16]; b1r[i] = b1g[i * 16 + col16]; }
#pragma unroll
    for (int i = 0; i < 4; i++) {
        b2r[i] = b2g[i * 16 + col16];
        gr[i] = lng[i * 16 + col16];
        br[i] = lnb[i * 16 + col16];
    }

    const bf16* wl = wimg + (size_t)lane * 8;  // frag blocks stride 512 elems
    const f32x4 vzero = {0.0f, 0.0f, 0.0f, 0.0f};
    const int r0 = wv * 32 + col16;     // A-frag row (mt=0)
    const int rw = wv * 32 + quad * 4;  // C/D row base (+ mt*16 + reg)
    const int sbase = blockIdx.x * 128;

    // ---- stage A tile: concat(x[row], eattr) for sorted slot s ----
    int vreg;  // row | dest<<16 of the row this thread staged (wave-local row = lane>>1)
    {
        const int el = tid >> 1, half = tid & 1;
        int2 v = prd[sbase + el];
        vreg = v.y;
        const int r = v.y & 0xFFFF;
        const float4* xs = (const float4*)(x + (size_t)r * 64);
        bf16* arow = atile + el * 104;
#pragma unroll
        for (int j = 0; j < 8; j++) {
            float4 vv = xs[half * 8 + j];
            bf16x4 u = {(bf16)vv.x, (bf16)vv.y, (bf16)vv.z, (bf16)vv.w};
            *(bf16x4*)(arow + half * 32 + j * 4) = u;
        }
        const float4* es = (const float4*)(eattr + (size_t)v.x * 32);
#pragma unroll
        for (int j = 0; j < 4; j++) {
            float4 vv = es[half * 4 + j];
            bf16x4 u = {(bf16)vv.x, (bf16)vv.y, (bf16)vv.z, (bf16)vv.w};
            *(bf16x4*)(arow + 64 + half * 16 + j * 4) = u;
        }
    }
    // wave staged exactly its own 32 rows -> no barrier needed anywhere

    // ---- layer 1: [32x96] @ [96x128], atile -> hid ----
    f32x4 acc1[2][8];
#pragma unroll
    for (int mt = 0; mt < 2; mt++)
#pragma unroll
        for (int nt = 0; nt < 8; nt++) acc1[mt][nt] = vzero;
#pragma unroll
    for (int ks = 0; ks < 3; ks++) {
        bf16x8 a0 = *(const bf16x8*)(atile + r0 * 104 + ks * 32 + quad * 8);
        bf16x8 a1 = *(const bf16x8*)(atile + (r0 + 16) * 104 + ks * 32 + quad * 8);
#pragma unroll
        for (int nt = 0; nt < 8; nt++) {
            bf16x8 b = *(const bf16x8*)(wl + (ks * 8 + nt) * 512);
            acc1[0][nt] = mfma_bf16(a0, b, acc1[0][nt]);
            acc1[1][nt] = mfma_bf16(a1, b, acc1[1][nt]);
        }
    }
#pragma unroll
    for (int mt = 0; mt < 2; mt++)
#pragma unroll
        for (int nt = 0; nt < 8; nt++)
#pragma unroll
            for (int rg = 0; rg < 4; rg++) {
                float v = acc1[mt][nt][rg] + b0r[nt];
                v = (v > 0.0f) ? v : 0.01f * v;
                hid[(rw + mt * 16 + rg) * 136 + nt * 16 + col16] = (bf16)v;
            }

    // ---- layer 2: [32x128] @ [128x128], hid -> hid ----
    bf16x8 a2[2][4];
#pragma unroll
    for (int mt = 0; mt < 2; mt++)
#pragma unroll
        for (int ks = 0; ks < 4; ks++)
            a2[mt][ks] = *(const bf16x8*)(hid + (r0 + mt * 16) * 136 + ks * 32 + quad * 8);
    f32x4 acc2[2][8];
#pragma unroll
    for (int mt = 0; mt < 2; mt++)
#pragma unroll
        for (int nt = 0; nt < 8; nt++) acc2[mt][nt] = vzero;
#pragma unroll
    for (int ks = 0; ks < 4; ks++) {
#pragma unroll
        for (int nt = 0; nt < 8; nt++) {
            bf16x8 b = *(const bf16x8*)(wl + 12288 + (ks * 8 + nt) * 512);
            acc2[0][nt] = mfma_bf16(a2[0][ks], b, acc2[0][nt]);
            acc2[1][nt] = mfma_bf16(a2[1][ks], b, acc2[1][nt]);
        }
    }
#pragma unroll
    for (int mt = 0; mt < 2; mt++)
#pragma unroll
        for (int nt = 0; nt < 8; nt++)
#pragma unroll
            for (int rg = 0; rg < 4; rg++) {
                float v = acc2[mt][nt][rg] + b1r[nt];
                v = (v > 0.0f) ? v : 0.01f * v;
                hid[(rw + mt * 16 + rg) * 136 + nt * 16 + col16] = (bf16)v;
            }

    // ---- layer 3: [32x128] @ [128x64] ----
    bf16x8 a3[2][4];
#pragma unroll
    for (int mt = 0; mt < 2; mt++)
#pragma unroll
        for (int ks = 0; ks < 4; ks++)
            a3[mt][ks] = *(const bf16x8*)(hid + (r0 + mt * 16) * 136 + ks * 32 + quad * 8);
    f32x4 acc3[2][4];
#pragma unroll
    for (int mt = 0; mt < 2; mt++)
#pragma unroll
        for (int nt = 0; nt < 4; nt++) acc3[mt][nt] = vzero;
#pragma unroll
    for (int ks = 0; ks < 4; ks++) {
#pragma unroll
        for (int nt = 0; nt < 4; nt++) {
            bf16x8 b = *(const bf16x8*)(wl + 28672 + (ks * 4 + nt) * 512);
            acc3[0][nt] = mfma_bf16(a3[0][ks], b, acc3[0][nt]);
            acc3[1][nt] = mfma_bf16(a3[1][ks], b, acc3[1][nt]);
        }
    }

    // ---- epilogue: bias + lrelu + LN(64) + run-merged atomic scatter ----
#pragma unroll
    for (int mt = 0; mt < 2; mt++) {
        float vals[4][4];  // [nt][rg]
        float s1[4] = {0.f, 0.f, 0.f, 0.f}, s2[4] = {0.f, 0.f, 0.f, 0.f};
#pragma unroll
        for (int nt = 0; nt < 4; nt++)
#pragma unroll
            for (int rg = 0; rg < 4; rg++) {
                float v = acc3[mt][nt][rg] + b2r[nt];
                v = (v > 0.0f) ? v : 0.01f * v;
                vals[nt][rg] = v;
                s1[rg] += v;
                s2[rg] += v * v;
            }
#pragma unroll
        for (int off2 = 1; off2 < 16; off2 <<= 1) {
#pragma unroll
            for (int rg = 0; rg < 4; rg++) {
                s1[rg] += __shfl_xor(s1[rg], off2);
                s2[rg] += __shfl_xor(s2[rg], off2);
            }
        }
        float o[4][4];
        int dr[4];
#pragma unroll
        for (int rg = 0; rg < 4; rg++) {
            float mu = s1[rg] * 0.015625f;
            float var = s2[rg] * 0.015625f - mu * mu;
            float rstd = rsqrtf(var + 1e-5f);
            // dest of wave-local row (mt*16+quad*4+rg), staged by lane 2*row
            dr[rg] = ((unsigned)__shfl(vreg, (mt * 16 + quad * 4 + rg) << 1)) >> 16;
#pragma unroll
            for (int nt = 0; nt < 4; nt++)
                o[nt][rg] = (vals[nt][rg] - mu) * rstd * gr[nt] + br[nt];
        }
        // run-merge consecutive equal destinations (edges dest-sorted)
        float run0 = o[0][0], run1 = o[1][0], run2 = o[2][0], run3 = o[3][0];
        int cur = dr[0];
#pragma unroll
        for (int rg = 1; rg < 4; rg++) {
            if (dr[rg] != cur) {
                float* dst = agg + (size_t)cur * 64 + col16;
                atomicAdd(dst, run0); atomicAdd(dst + 16, run1);
                atomicAdd(dst + 32, run2); atomicAdd(dst + 48, run3);
                run0 = o[0][rg]; run1 = o[1][rg]; run2 = o[2][rg]; run3 = o[3][rg];
                cur = dr[rg];
            } else {
                run0 += o[0][rg]; run1 += o[1][rg]; run2 += o[2][rg]; run3 += o[3][rg];
            }
        }
        float* dst = agg + (size_t)cur * 64 + col16;
        atomicAdd(dst, run0); atomicAdd(dst + 16, run1);
        atomicAdd(dst + 32, run2); atomicAdd(dst + 48, run3);
    }
}

// ============ node_mlp: R5 register-gather, 64-thread version ============
__global__ __launch_bounds__(64, 4) void node_mlp(
    const float* __restrict__ x, const float* __restrict__ agg,
    const int* __restrict__ hist, const bf16* __restrict__ wimg,
    const float* __restrict__ b0g, const float* __restrict__ b1g,
    const float* __restrict__ b2g, const float* __restrict__ lng,
    const float* __restrict__ lnb, float* __restrict__ out) {
    __shared__ __align__(16) bf16 hid[32 * 136];

    const int lane = threadIdx.x;
    const int col16 = lane & 15;
    const int quad = lane >> 4;

    float b0r[8], b1r[8], b2r[4], gr[4], br[4];
#pragma unroll
    for (int i = 0; i < 8; i++) { b0r[i] = b0g[i * 16 + col16]; b1r[i] = b1g[i * 16 + col16]; }
#pragma unroll
    for (int i = 0; i < 4; i++) {
        b2r[i] = b2g[i * 16 + col16];
        gr[i] = lng[i * 16 + col16];
        br[i] = lnb[i * 16 + col16];
    }

    const bf16* wl = wimg + 36864 + (size_t)lane * 8;
    const f32x4 vzero = {0.0f, 0.0f, 0.0f, 0.0f};
    const int nbase = blockIdx.x * 32;

    // ---- layer-1 A-frags direct: concat(x[i], agg[i]/max(cnt,1)) ----
    bf16x8 a1[2][4];
#pragma unroll
    for (int mt = 0; mt < 2; mt++) {
        int i = nbase + col16 + 16 * mt;
        if (i >= NNODES) i = NNODES - 1;  // clamp; tail rows never stored
        const float4* xr = (const float4*)(x + (size_t)i * 64);
        float4 x0 = xr[quad * 2], x1 = xr[quad * 2 + 1];
        float4 x2 = xr[8 + quad * 2], x3 = xr[8 + quad * 2 + 1];
        int c = hist[i];
        float inv = 1.0f / (float)(c > 1 ? c : 1);
        const float4* ar = (const float4*)(agg + (size_t)i * 64);
        float4 g0 = ar[quad * 2], g1 = ar[quad * 2 + 1];
        float4 g2 = ar[8 + quad * 2], g3 = ar[8 + quad * 2 + 1];
        a1[mt][0] = pack8(x0, x1);
        a1[mt][1] = pack8(x2, x3);
        float4 h0 = {g0.x * inv, g0.y * inv, g0.z * inv, g0.w * inv};
        float4 h1 = {g1.x * inv, g1.y * inv, g1.z * inv, g1.w * inv};
        float4 h2 = {g2.x * inv, g2.y * inv, g2.z * inv, g2.w * inv};
        float4 h3 = {g3.x * inv, g3.y * inv, g3.z * inv, g3.w * inv};
        a1[mt][2] = pack8(h0, h1);
        a1[mt][3] = pack8(h2, h3);
    }

    // ---- layer 1: [32x128] @ [128x128] ----
    f32x4 acc1[2][8];
#pragma unroll
    for (int mt = 0; mt < 2; mt++)
#pragma unroll
        for (int nt = 0; nt < 8; nt++) acc1[mt][nt] = vzero;
#pragma unroll
    for (int ks = 0; ks < 4; ks++) {
#pragma unroll
        for (int nt = 0; nt < 8; nt++) {
            bf16x8 b = *(const bf16x8*)(wl + (ks * 8 + nt) * 512);
            acc1[0][nt] = mfma_bf16(a1[0][ks], b, acc1[0][nt]);
            acc1[1][nt] = mfma_bf16(a1[1][ks], b, acc1[1][nt]);
        }
    }
    const int rw = quad * 4;
#pragma unroll
    for (int mt = 0; mt < 2; mt++)
#pragma unroll
        for (int nt = 0; nt < 8; nt++)
#pragma unroll
            for (int rg = 0; rg < 4; rg++) {
                float v = acc1[mt][nt][rg] + b0r[nt];
                v = (v > 0.0f) ? v : 0.01f * v;
                hid[(rw + mt * 16 + rg) * 136 + nt * 16 + col16] = (bf16)v;
            }

    // ---- layer 2 ----
    bf16x8 a2[2][4];
#pragma unroll
    for (int mt = 0; mt < 2; mt++)
#pragma unroll
        for (int ks = 0; ks < 4; ks++)
            a2[mt][ks] = *(const bf16x8*)(hid + (col16 + 16 * mt) * 136 + ks * 32 + quad * 8);
    f32x4 acc2[2][8];
#pragma unroll
    for (int mt = 0; mt < 2; mt++)
#pragma unroll
        for (int nt = 0; nt < 8; nt++) acc2[mt][nt] = vzero;
#pragma unroll
    for (int ks = 0; ks < 4; ks++) {
#pragma unroll
        for (int nt = 0; nt < 8; nt++) {
            bf16x8 b = *(const bf16x8*)(wl + 16384 + (ks * 8 + nt) * 512);
            acc2[0][nt] = mfma_bf16(a2[0][ks], b, acc2[0][nt]);
            acc2[1][nt] = mfma_bf16(a2[1][ks], b, acc2[1][nt]);
        }
    }
#pragma unroll
    for (int mt = 0; mt < 2; mt++)
#pragma unroll
        for (int nt = 0; nt < 8; nt++)
#pragma unroll
            for (int rg = 0; rg < 4; rg++) {
                float v = acc2[mt][nt][rg] + b1r[nt];
                v = (v > 0.0f) ? v : 0.01f * v;
                hid[(rw + mt * 16 + rg) * 136 + nt * 16 + col16] = (bf16)v;
            }

    // ---- layer 3 ----
    bf16x8 a3[2][4];
#pragma unroll
    for (int mt = 0; mt < 2; mt++)
#pragma unroll
        for (int ks = 0; ks < 4; ks++)
            a3[mt][ks] = *(const bf16x8*)(hid + (col16 + 16 * mt) * 136 + ks * 32 + quad * 8);
    f32x4 acc3[2][4];
#pragma unroll
    for (int mt = 0; mt < 2; mt++)
#pragma unroll
        for (int nt = 0; nt < 4; nt++) acc3[mt][nt] = vzero;
#pragma unroll
    for (int ks = 0; ks < 4; ks++) {
#pragma unroll
        for (int nt = 0; nt < 4; nt++) {
            bf16x8 b = *(const bf16x8*)(wl + 32768 + (ks * 4 + nt) * 512);
            acc3[0][nt] = mfma_bf16(a3[0][ks], b, acc3[0][nt]);
            acc3[1][nt] = mfma_bf16(a3[1][ks], b, acc3[1][nt]);
        }
    }

    // ---- epilogue: bias + lrelu + LN + store ----
#pragma unroll
    for (int mt = 0; mt < 2; mt++) {
        float vals[4][4];
        float s1[4] = {0.f, 0.f, 0.f, 0.f}, s2[4] = {0.f, 0.f, 0.f, 0.f};
#pragma unroll
        for (int nt = 0; nt < 4; nt++)
#pragma unroll
            for (int rg = 0; rg < 4; rg++) {
                float v = acc3[mt][nt][rg] + b2r[nt];
                v = (v > 0.0f) ? v : 0.01f * v;
                vals[nt][rg] = v;
                s1[rg] += v;
                s2[rg] += v * v;
            }
#pragma unroll
        for (int off2 = 1; off2 < 16; off2 <<= 1) {
#pragma unroll
            for (int rg = 0; rg < 4; rg++) {
                s1[rg] += __shfl_xor(s1[rg], off2);
                s2[rg] += __shfl_xor(s2[rg], off2);
            }
        }
#pragma unroll
        for (int rg = 0; rg < 4; rg++) {
            float mu = s1[rg] * 0.015625f;
            float var = s2[rg] * 0.015625f - mu * mu;
            float rstd = rsqrtf(var + 1e-5f);
            int i = nbase + mt * 16 + quad * 4 + rg;
            if (i < NNODES) {
#pragma unroll
                for (int nt = 0; nt < 4; nt++) {
                    float o = (vals[nt][rg] - mu) * rstd * gr[nt] + br[nt];
                    out[(size_t)i * 64 + nt * 16 + col16] = o;
                }
            }
        }
    }
}

extern "C" void kernel_launch(void* const* d_in, const int* in_sizes, int n_in,
                              void* d_out, int out_size, void* d_ws, size_t ws_size,
                              hipStream_t stream) {
    (void)in_sizes; (void)n_in; (void)out_size; (void)ws_size;
    const float* x     = (const float*)d_in[0];
    const int*   eidx  = (const int*)d_in[1];
    const float* eattr = (const float*)d_in[2];
    const float* m1w0 = (const float*)d_in[5];
    const float* m1b0 = (const float*)d_in[6];
    const float* m1w1 = (const float*)d_in[7];
    const float* m1b1 = (const float*)d_in[8];
    const float* m1w2 = (const float*)d_in[9];
    const float* m1b2 = (const float*)d_in[10];
    const float* ln1g = (const float*)d_in[11];
    const float* ln1b = (const float*)d_in[12];
    const float* m2w0 = (const float*)d_in[13];
    const float* m2b0 = (const float*)d_in[14];
    const float* m2w1 = (const float*)d_in[15];
    const float* m2b1 = (const float*)d_in[16];
    const float* m2w2 = (const float*)d_in[17];
    const float* m2b2 = (const float*)d_in[18];
    const float* ln2g = (const float*)d_in[19];
    const float* ln2b = (const float*)d_in[20];

    // ---- workspace layout ----
    char* ws = (char*)d_ws;
    float* agg  = (float*)ws;                          // 12,800,000 B
    int*   hist = (int*)(ws + 12800000);               //    200,000 B
    int*   off  = (int*)(ws + 13000000);               //    200,000 B
    int*   csum = (int*)(ws + 13200000);               //        512 B
    int2*  prd  = (int2*)(ws + 13200512);              //  6,400,000 B
    bf16*  wimg = (bf16*)(ws + 19600512);              //    155,648 B

    hipMemsetAsync(d_ws, 0, 13000000, stream);  // agg + hist
    prep_weights<<<304, 256, 0, stream>>>(m1w0, m1w1, m1w2, m2w0, m2w1, m2w2, wimg);
    hist_kernel<<<1563, 512, 0, stream>>>(eidx + NEDGES, hist);
    scanA<<<98, 512, 0, stream>>>(hist, off, csum);
    scanB<<<1, 128, 0, stream>>>(csum);
    scatter_kernel<<<1563, 512, 0, stream>>>(eidx, off, csum, prd);
    edge_mlp<<<6250, 256, 0, stream>>>(x, prd, eattr, wimg, m1b0, m1b1, m1b2,
                                       ln1g, ln1b, agg);
    node_mlp<<<1563, 64, 0, stream>>>(x, agg, hist, wimg,
                                      m2b0, m2b1, m2b2, ln2g, ln2b, (float*)d_out);
}